// Round 15
// baseline (110.313 us; speedup 1.0000x reference)
//
#include <hip/hip_runtime.h>

#define B_ 512
#define L_ 64
#define H_ 256
#define OUT_ 2048

typedef short bf16x8 __attribute__((ext_vector_type(8)));
typedef float f32x4 __attribute__((ext_vector_type(4)));

static __device__ __forceinline__ unsigned short f2bf(float f) {
  union { float f; unsigned int u; } v; v.f = f;
  unsigned int r = (v.u + 0x7FFFu + ((v.u >> 16) & 1u)) >> 16;
  return (unsigned short)r;
}
static __device__ __forceinline__ float bf2f(unsigned short s) {
  union { unsigned int u; float f; } v; v.u = ((unsigned int)s) << 16;
  return v.f;
}

// ---------------------------------------------------------------------------
// Pack Wc (256x2048 f32) and Wp (256x256 f32) into MFMA-fragment-major bf16:
// frag (col16, kt): 64 lanes x 16B; lane l holds
//   B[k = kt*32 + (l>>4)*8 + i][n = col16*16 + (l&15)], i = 0..7.
// ---------------------------------------------------------------------------
__global__ __launch_bounds__(256) void pack_kernel(
    const float* __restrict__ Wc, const float* __restrict__ Wp,
    unsigned short* __restrict__ WcB, unsigned short* __restrict__ WpB) {
  int bid = blockIdx.x;
  const float* W;
  unsigned short* dst;
  int ncols, col16;
  if (bid < 128) { W = Wc; dst = WcB; ncols = OUT_; col16 = bid; }
  else           { W = Wp; dst = WpB; ncols = H_;   col16 = bid - 128; }
  int tid = threadIdx.x, l = tid & 63, q = tid >> 6;
  int n = col16 * 16 + (l & 15), g = l >> 4;
#pragma unroll
  for (int kk = 0; kk < 2; ++kk) {
    int kt = q + kk * 4;
    bf16x8 v;
#pragma unroll
    for (int i = 0; i < 8; ++i)
      v[i] = (short)f2bf(W[(size_t)(kt * 32 + g * 8 + i) * ncols + n]);
    *(bf16x8*)&dst[(size_t)(col16 * 8 + kt) * 512 + l * 8] = v;
  }
}

// ---------------------------------------------------------------------------
// Fused kernel (R10 code verbatim except bid decode), grid = 2*B_, 256 thr,
// 4 WG/CU, one round. bid decode pairs both halves of a batch onto the SAME
// XCD (dispatch round-robins bid%8 across XCDs; bid and bid+8 share an XCD),
// so the duplicated 64KB mol read L2-hits for the second WG.
// zbuf swizzle: ushort index ^= (row&7)<<3.
// ---------------------------------------------------------------------------
__global__ __launch_bounds__(256, 2) void fused_kernel(
    const float* __restrict__ mol, const int* __restrict__ pidx_g,
    const float* __restrict__ bp, const unsigned short* __restrict__ WpB,
    const unsigned short* __restrict__ WcB, const float* __restrict__ bc,
    float* __restrict__ out) {
  __shared__ unsigned short zbuf[65 * H_];  // 33280 B (row 64 = dummy slot)
  __shared__ int pidx[L_];
  __shared__ int cnt_i[64];
  __shared__ unsigned short scale_s[64];
  __shared__ int lvlcnt[64];
  __shared__ int lvlbase[64];
  __shared__ int chkbase[64];
  __shared__ int order_s[64];
  __shared__ int cstart_s[64];
  __shared__ int ccnt_s[64];
  __shared__ int nchunks_s;

  int bid = blockIdx.x;
  int b = ((bid >> 4) << 3) | (bid & 7);  // XCD-pairing
  int half = (bid >> 3) & 1;
  int tid = threadIdx.x;
  int wv = tid >> 6, l = tid & 63, g = l >> 4, c = l & 15;

  if (tid < 64) pidx[tid] = pidx_g[b * L_ + tid];

  // ---- stage mol -> zbuf (bf16, swizzled 16B chunks) ----
  const float* molb = mol + (size_t)b * L_ * H_;
#pragma unroll
  for (int i = 0; i < 8; ++i) {
    int idx = tid + i * 256;            // 16B chunk id, 0..2047
    int t = idx >> 5, h0 = (idx & 31) * 8;
    f32x4 lo = *(const f32x4*)&molb[t * H_ + h0];
    f32x4 hi = *(const f32x4*)&molb[t * H_ + h0 + 4];
    bf16x8 v;
#pragma unroll
    for (int q = 0; q < 4; ++q) { v[q] = (short)f2bf(lo[q]); v[q + 4] = (short)f2bf(hi[q]); }
    *(bf16x8*)&zbuf[(t * H_ + h0) ^ ((t & 7) << 3)] = v;
  }

  // ---- wave 0: counts, scales, level schedule (LDS-atomic ranks) ----
  if (tid < 64) {
    int t = tid;
    cnt_i[t] = 0;
    lvlcnt[t] = 0;
    int pp = pidx[t];
    if (t >= 1) atomicAdd(&cnt_i[pp], 1);
    int lev = (t == 0) ? 0 : 1;
#pragma unroll
    for (int it = 0; it < 6; ++it) {
      int dp = __shfl(lev, pp);
      int pp2 = __shfl(pp, pp);
      lev += dp;
      pp = pp2;
    }
    int cc = (t >= 1) ? (cnt_i[pidx[t]] - 1) : 0;
    scale_s[t] = (t >= 1 && cc > 0) ? f2bf(1.f / (float)cc) : 0;
    int rank = 0;
    if (t >= 1) rank = atomicAdd(&lvlcnt[lev], 1);
    int lc = lvlcnt[t];
    int nchk = (lc + 15) >> 4;
    int offx = lc, chkx = nchk;
#pragma unroll
    for (int d = 1; d < 64; d <<= 1) {
      int u = __shfl_up(offx, d);
      int v2 = __shfl_up(chkx, d);
      if (t >= d) { offx += u; chkx += v2; }
    }
    lvlbase[t] = offx - lc;
    chkbase[t] = chkx - nchk;
    if (t == 63) nchunks_s = chkx;
    if (t >= 1) {
      int pos = lvlbase[lev] + rank;
      order_s[pos] = t;
      if ((rank & 15) == 0) {
        int cid = chkbase[lev] + (rank >> 4);
        cstart_s[cid] = pos;
        ccnt_s[cid] = min(16, lvlcnt[lev] - rank);
      }
    }
  }
  __syncthreads();

  // ---- sibling means via MFMA: sib^T = mol^T @ G^T ----
  {
    int pv[2][8];
#pragma unroll
    for (int kt = 0; kt < 2; ++kt)
#pragma unroll
      for (int i = 0; i < 8; ++i) pv[kt][i] = pidx[kt * 32 + g * 8 + i];
    bf16x8 bfr[4][2];
#pragma unroll
    for (int nt = 0; nt < 4; ++nt) {
      int tn = nt * 16 + c;
      int pt = pidx[tn];
      unsigned short scl = scale_s[tn];
#pragma unroll
      for (int kt = 0; kt < 2; ++kt) {
        bf16x8 bv;
#pragma unroll
        for (int i = 0; i < 8; ++i) {
          int tp = kt * 32 + g * 8 + i;
          bv[i] = (tp >= 1 && tp != tn && pv[kt][i] == pt) ? (short)scl : (short)0;
        }
        bfr[nt][kt] = bv;
      }
    }
#pragma unroll
    for (int mtl = 0; mtl < 4; ++mtl) {
      int mtg = wv * 4 + mtl;        // global h-tile 0..15
      int colh = mtg * 16 + c;
      bf16x8 afr[2];
#pragma unroll
      for (int kt = 0; kt < 2; ++kt) {
        bf16x8 av;
#pragma unroll
        for (int i = 0; i < 8; ++i) {
          int tp = kt * 32 + g * 8 + i;
          av[i] = (short)zbuf[(tp * H_ + colh) ^ ((tp & 7) << 3)];
        }
        afr[kt] = av;
      }
      f32x4 acc4[4] = {};
#pragma unroll
      for (int nt = 0; nt < 4; ++nt)
#pragma unroll
        for (int kt = 0; kt < 2; ++kt)
          acc4[nt] = __builtin_amdgcn_mfma_f32_16x16x32_bf16(afr[kt], bfr[nt][kt], acc4[nt], 0, 0, 0);
      // scatter: C row=(l>>4)*4+j -> h, col=c -> t (scalar, bank-clean)
#pragma unroll
      for (int nt = 0; nt < 4; ++nt) {
        int ts = nt * 16 + c;
        int swn = (ts & 7) << 3;
#pragma unroll
        for (int j = 0; j < 4; ++j) {
          int h = mtg * 16 + g * 4 + j;
          zbuf[(ts * H_ + h) ^ swn] = f2bf(acc4[nt][j]);
        }
      }
    }
  }

  // ---- Wp B-fragments (per-wave 64-col slice), step-invariant registers ----
  bf16x8 wfr[4][8];
#pragma unroll
  for (int nt = 0; nt < 4; ++nt)
#pragma unroll
    for (int kt = 0; kt < 8; ++kt)
      wfr[nt][kt] = *(const bf16x8*)&WpB[(size_t)((wv * 4 + nt) * 8 + kt) * 512 + l * 8];
  float bpv[4];
#pragma unroll
  for (int nt = 0; nt < 4; ++nt) bpv[nt] = bp[wv * 64 + nt * 16 + c];
  __syncthreads();

  // ---- level-parallel recurrence: one M=16 MFMA round per chunk ----
  int nch = nchunks_s;
  for (int ch = 0; ch < nch; ++ch) {
    int cs = cstart_s[ch], cc = ccnt_s[ch];
    int node = (c < cc) ? order_s[cs + c] : 64;  // A row m = c
    int par = (node < 64) ? pidx[node] : 0;
    int sp = (par & 7) << 3;
    f32x4 a0 = {0.f, 0.f, 0.f, 0.f};
    f32x4 a1 = {0.f, 0.f, 0.f, 0.f};
    f32x4 a2 = {0.f, 0.f, 0.f, 0.f};
    f32x4 a3 = {0.f, 0.f, 0.f, 0.f};
#pragma unroll
    for (int kt = 0; kt < 8; ++kt) {
      bf16x8 av = *(const bf16x8*)&zbuf[par * H_ + ((kt * 32 + g * 8) ^ sp)];
      a0 = __builtin_amdgcn_mfma_f32_16x16x32_bf16(av, wfr[0][kt], a0, 0, 0, 0);
      a1 = __builtin_amdgcn_mfma_f32_16x16x32_bf16(av, wfr[1][kt], a1, 0, 0, 0);
      a2 = __builtin_amdgcn_mfma_f32_16x16x32_bf16(av, wfr[2][kt], a2, 0, 0, 0);
      a3 = __builtin_amdgcn_mfma_f32_16x16x32_bf16(av, wfr[3][kt], a3, 0, 0, 0);
    }
    // epilogue: C row m=(l>>4)*4+j -> node slot m, col=c (scalar, bank-clean)
#pragma unroll
    for (int j = 0; j < 4; ++j) {
      int m = g * 4 + j;
      int nd = (m < cc) ? order_s[cs + m] : 64;
      int swn = (nd & 7) << 3;
      int base = nd * H_ + wv * 64 + c;
      int i0 = (base + 0) ^ swn, i1 = (base + 16) ^ swn;
      int i2 = (base + 32) ^ swn, i3 = (base + 48) ^ swn;
      float v0 = fmaxf(a0[j] + bpv[0], 0.f) + bf2f(zbuf[i0]);
      float v1 = fmaxf(a1[j] + bpv[1], 0.f) + bf2f(zbuf[i1]);
      float v2 = fmaxf(a2[j] + bpv[2], 0.f) + bf2f(zbuf[i2]);
      float v3 = fmaxf(a3[j] + bpv[3], 0.f) + bf2f(zbuf[i3]);
      zbuf[i0] = f2bf(v0);
      zbuf[i1] = f2bf(v1);
      zbuf[i2] = f2bf(v2);
      zbuf[i3] = f2bf(v3);
    }
    __syncthreads();
  }

  // ---- logits GEMM from zbuf: this WG covers cols [half*1024, +1024) ----
#pragma unroll 1
  for (int nc = 0; nc < 4; ++nc) {
    int colbase = half * 1024 + wv * 256 + nc * 64;
    float bcv[4];
#pragma unroll
    for (int nt = 0; nt < 4; ++nt) bcv[nt] = bc[colbase + nt * 16 + c];
    f32x4 acc[4][4] = {};
#pragma unroll
    for (int kt = 0; kt < 8; ++kt) {
      bf16x8 a[4], bfr[4];
#pragma unroll
      for (int mt = 0; mt < 4; ++mt) {
        int r = mt * 16 + c;
        a[mt] = *(const bf16x8*)&zbuf[r * H_ + ((kt * 32 + g * 8) ^ ((r & 7) << 3))];
      }
#pragma unroll
      for (int nt = 0; nt < 4; ++nt) {
        int col16 = (colbase >> 4) + nt;
        bfr[nt] = *(const bf16x8*)&WcB[(size_t)(col16 * 8 + kt) * 512 + l * 8];
      }
#pragma unroll
      for (int nt = 0; nt < 4; ++nt)
#pragma unroll
        for (int mt = 0; mt < 4; ++mt)
          acc[mt][nt] = __builtin_amdgcn_mfma_f32_16x16x32_bf16(
              a[mt], bfr[nt], acc[mt][nt], 0, 0, 0);
    }
#pragma unroll
    for (int mt = 0; mt < 4; ++mt)
#pragma unroll
      for (int nt = 0; nt < 4; ++nt) {
        int col = colbase + nt * 16 + c;
#pragma unroll
        for (int j = 0; j < 4; ++j) {
          int rt = mt * 16 + g * 4 + j;  // C: row=(l>>4)*4+reg, col=l&15
          out[(size_t)(b * 64 + rt) * OUT_ + col] = acc[mt][nt][j] + bcv[nt];
        }
      }
  }
}

extern "C" void kernel_launch(void* const* d_in, const int* in_sizes, int n_in,
                              void* d_out, int out_size, void* d_ws, size_t ws_size,
                              hipStream_t stream) {
  const float* mol = (const float*)d_in[0];
  const int* pidx = (const int*)d_in[1];
  const float* Wp = (const float*)d_in[2];
  const float* bp = (const float*)d_in[3];
  const float* Wc = (const float*)d_in[4];
  const float* bc = (const float*)d_in[5];
  float* out = (float*)d_out;

  unsigned short* WcB = (unsigned short*)d_ws;                  // 1 MB
  unsigned short* WpB = WcB + (size_t)128 * 8 * 512;            // 128 KB

  pack_kernel<<<144, 256, 0, stream>>>(Wc, Wp, WcB, WpB);
  fused_kernel<<<2 * B_, 256, 0, stream>>>(mol, pidx, bp, WpB, WcB, bc, out);
}

// Round 16
// 104.755 us; speedup vs baseline: 1.0531x; 1.0531x over previous
//
#include <hip/hip_runtime.h>

#define B_ 512
#define L_ 64
#define H_ 256
#define OUT_ 2048

typedef short bf16x8 __attribute__((ext_vector_type(8)));
typedef float f32x4 __attribute__((ext_vector_type(4)));

static __device__ __forceinline__ unsigned short f2bf(float f) {
  union { float f; unsigned int u; } v; v.f = f;
  unsigned int r = (v.u + 0x7FFFu + ((v.u >> 16) & 1u)) >> 16;
  return (unsigned short)r;
}
static __device__ __forceinline__ float bf2f(unsigned short s) {
  union { unsigned int u; float f; } v; v.u = ((unsigned int)s) << 16;
  return v.f;
}

// ---------------------------------------------------------------------------
// Pack Wc (256x2048 f32) and Wp (256x256 f32) into MFMA-fragment-major bf16:
// frag (col16, kt): 64 lanes x 16B; lane l holds
//   B[k = kt*32 + (l>>4)*8 + i][n = col16*16 + (l&15)], i = 0..7.
// ---------------------------------------------------------------------------
__global__ __launch_bounds__(256) void pack_kernel(
    const float* __restrict__ Wc, const float* __restrict__ Wp,
    unsigned short* __restrict__ WcB, unsigned short* __restrict__ WpB) {
  int bid = blockIdx.x;
  const float* W;
  unsigned short* dst;
  int ncols, col16;
  if (bid < 128) { W = Wc; dst = WcB; ncols = OUT_; col16 = bid; }
  else           { W = Wp; dst = WpB; ncols = H_;   col16 = bid - 128; }
  int tid = threadIdx.x, l = tid & 63, q = tid >> 6;
  int n = col16 * 16 + (l & 15), g = l >> 4;
#pragma unroll
  for (int kk = 0; kk < 2; ++kk) {
    int kt = q + kk * 4;
    bf16x8 v;
#pragma unroll
    for (int i = 0; i < 8; ++i)
      v[i] = (short)f2bf(W[(size_t)(kt * 32 + g * 8 + i) * ncols + n]);
    *(bf16x8*)&dst[(size_t)(col16 * 8 + kt) * 512 + l * 8] = v;
  }
}

// ---------------------------------------------------------------------------
// Fused kernel (champion, R10), grid = 2*B_ (WG = (batch, col-half)), 256 thr,
// 4 WG/CU, single round. NO min-occupancy launch-bounds arg (R6/R9: it forces
// VGPR=64 + scratch spills).
//  1. stage mol -> zbuf (bf16, swizzled)
//  2. wave0: cnt/scale + level schedule (LDS-atomic ranks)
//  3. sibling means via MFMA: sib^T = mol^T @ G^T (G from pidx/scale in regs)
//  4. level-parallel recurrence (M=16 MFMA chunk per tree level slice)
//  5. logits GEMM for cols [half*1024, +1024)
// zbuf swizzle: ushort index ^= (row&7)<<3.
// ---------------------------------------------------------------------------
__global__ __launch_bounds__(256, 2) void fused_kernel(
    const float* __restrict__ mol, const int* __restrict__ pidx_g,
    const float* __restrict__ bp, const unsigned short* __restrict__ WpB,
    const unsigned short* __restrict__ WcB, const float* __restrict__ bc,
    float* __restrict__ out) {
  __shared__ unsigned short zbuf[65 * H_];  // 33280 B (row 64 = dummy slot)
  __shared__ int pidx[L_];
  __shared__ int cnt_i[64];
  __shared__ unsigned short scale_s[64];
  __shared__ int lvlcnt[64];
  __shared__ int lvlbase[64];
  __shared__ int chkbase[64];
  __shared__ int order_s[64];
  __shared__ int cstart_s[64];
  __shared__ int ccnt_s[64];
  __shared__ int nchunks_s;

  int bid = blockIdx.x;
  int b = bid >> 1, half = bid & 1;
  int tid = threadIdx.x;
  int wv = tid >> 6, l = tid & 63, g = l >> 4, c = l & 15;

  if (tid < 64) pidx[tid] = pidx_g[b * L_ + tid];

  // ---- stage mol -> zbuf (bf16, swizzled 16B chunks) ----
  const float* molb = mol + (size_t)b * L_ * H_;
#pragma unroll
  for (int i = 0; i < 8; ++i) {
    int idx = tid + i * 256;            // 16B chunk id, 0..2047
    int t = idx >> 5, h0 = (idx & 31) * 8;
    f32x4 lo = *(const f32x4*)&molb[t * H_ + h0];
    f32x4 hi = *(const f32x4*)&molb[t * H_ + h0 + 4];
    bf16x8 v;
#pragma unroll
    for (int q = 0; q < 4; ++q) { v[q] = (short)f2bf(lo[q]); v[q + 4] = (short)f2bf(hi[q]); }
    *(bf16x8*)&zbuf[(t * H_ + h0) ^ ((t & 7) << 3)] = v;
  }

  // ---- wave 0: counts, scales, level schedule (LDS-atomic ranks) ----
  if (tid < 64) {
    int t = tid;
    cnt_i[t] = 0;
    lvlcnt[t] = 0;
    int pp = pidx[t];
    if (t >= 1) atomicAdd(&cnt_i[pp], 1);
    int lev = (t == 0) ? 0 : 1;
#pragma unroll
    for (int it = 0; it < 6; ++it) {
      int dp = __shfl(lev, pp);
      int pp2 = __shfl(pp, pp);
      lev += dp;
      pp = pp2;
    }
    int cc = (t >= 1) ? (cnt_i[pidx[t]] - 1) : 0;
    scale_s[t] = (t >= 1 && cc > 0) ? f2bf(1.f / (float)cc) : 0;
    int rank = 0;
    if (t >= 1) rank = atomicAdd(&lvlcnt[lev], 1);
    int lc = lvlcnt[t];
    int nchk = (lc + 15) >> 4;
    int offx = lc, chkx = nchk;
#pragma unroll
    for (int d = 1; d < 64; d <<= 1) {
      int u = __shfl_up(offx, d);
      int v2 = __shfl_up(chkx, d);
      if (t >= d) { offx += u; chkx += v2; }
    }
    lvlbase[t] = offx - lc;
    chkbase[t] = chkx - nchk;
    if (t == 63) nchunks_s = chkx;
    if (t >= 1) {
      int pos = lvlbase[lev] + rank;
      order_s[pos] = t;
      if ((rank & 15) == 0) {
        int cid = chkbase[lev] + (rank >> 4);
        cstart_s[cid] = pos;
        ccnt_s[cid] = min(16, lvlcnt[lev] - rank);
      }
    }
  }
  __syncthreads();

  // ---- sibling means via MFMA: sib^T = mol^T @ G^T ----
  {
    int pv[2][8];
#pragma unroll
    for (int kt = 0; kt < 2; ++kt)
#pragma unroll
      for (int i = 0; i < 8; ++i) pv[kt][i] = pidx[kt * 32 + g * 8 + i];
    bf16x8 bfr[4][2];
#pragma unroll
    for (int nt = 0; nt < 4; ++nt) {
      int tn = nt * 16 + c;
      int pt = pidx[tn];
      unsigned short scl = scale_s[tn];
#pragma unroll
      for (int kt = 0; kt < 2; ++kt) {
        bf16x8 bv;
#pragma unroll
        for (int i = 0; i < 8; ++i) {
          int tp = kt * 32 + g * 8 + i;
          bv[i] = (tp >= 1 && tp != tn && pv[kt][i] == pt) ? (short)scl : (short)0;
        }
        bfr[nt][kt] = bv;
      }
    }
#pragma unroll
    for (int mtl = 0; mtl < 4; ++mtl) {
      int mtg = wv * 4 + mtl;        // global h-tile 0..15
      int colh = mtg * 16 + c;
      bf16x8 afr[2];
#pragma unroll
      for (int kt = 0; kt < 2; ++kt) {
        bf16x8 av;
#pragma unroll
        for (int i = 0; i < 8; ++i) {
          int tp = kt * 32 + g * 8 + i;
          av[i] = (short)zbuf[(tp * H_ + colh) ^ ((tp & 7) << 3)];
        }
        afr[kt] = av;
      }
      f32x4 acc4[4] = {};
#pragma unroll
      for (int nt = 0; nt < 4; ++nt)
#pragma unroll
        for (int kt = 0; kt < 2; ++kt)
          acc4[nt] = __builtin_amdgcn_mfma_f32_16x16x32_bf16(afr[kt], bfr[nt][kt], acc4[nt], 0, 0, 0);
      // scatter: C row=(l>>4)*4+j -> h, col=c -> t (scalar, bank-clean)
#pragma unroll
      for (int nt = 0; nt < 4; ++nt) {
        int ts = nt * 16 + c;
        int swn = (ts & 7) << 3;
#pragma unroll
        for (int j = 0; j < 4; ++j) {
          int h = mtg * 16 + g * 4 + j;
          zbuf[(ts * H_ + h) ^ swn] = f2bf(acc4[nt][j]);
        }
      }
    }
  }

  // ---- Wp B-fragments (per-wave 64-col slice), step-invariant registers ----
  bf16x8 wfr[4][8];
#pragma unroll
  for (int nt = 0; nt < 4; ++nt)
#pragma unroll
    for (int kt = 0; kt < 8; ++kt)
      wfr[nt][kt] = *(const bf16x8*)&WpB[(size_t)((wv * 4 + nt) * 8 + kt) * 512 + l * 8];
  float bpv[4];
#pragma unroll
  for (int nt = 0; nt < 4; ++nt) bpv[nt] = bp[wv * 64 + nt * 16 + c];
  __syncthreads();

  // ---- level-parallel recurrence: one M=16 MFMA round per chunk ----
  int nch = nchunks_s;
  for (int ch = 0; ch < nch; ++ch) {
    int cs = cstart_s[ch], cc = ccnt_s[ch];
    int node = (c < cc) ? order_s[cs + c] : 64;  // A row m = c
    int par = (node < 64) ? pidx[node] : 0;
    int sp = (par & 7) << 3;
    f32x4 a0 = {0.f, 0.f, 0.f, 0.f};
    f32x4 a1 = {0.f, 0.f, 0.f, 0.f};
    f32x4 a2 = {0.f, 0.f, 0.f, 0.f};
    f32x4 a3 = {0.f, 0.f, 0.f, 0.f};
#pragma unroll
    for (int kt = 0; kt < 8; ++kt) {
      bf16x8 av = *(const bf16x8*)&zbuf[par * H_ + ((kt * 32 + g * 8) ^ sp)];
      a0 = __builtin_amdgcn_mfma_f32_16x16x32_bf16(av, wfr[0][kt], a0, 0, 0, 0);
      a1 = __builtin_amdgcn_mfma_f32_16x16x32_bf16(av, wfr[1][kt], a1, 0, 0, 0);
      a2 = __builtin_amdgcn_mfma_f32_16x16x32_bf16(av, wfr[2][kt], a2, 0, 0, 0);
      a3 = __builtin_amdgcn_mfma_f32_16x16x32_bf16(av, wfr[3][kt], a3, 0, 0, 0);
    }
    // epilogue: C row m=(l>>4)*4+j -> node slot m, col=c (scalar, bank-clean)
#pragma unroll
    for (int j = 0; j < 4; ++j) {
      int m = g * 4 + j;
      int nd = (m < cc) ? order_s[cs + m] : 64;
      int swn = (nd & 7) << 3;
      int base = nd * H_ + wv * 64 + c;
      int i0 = (base + 0) ^ swn, i1 = (base + 16) ^ swn;
      int i2 = (base + 32) ^ swn, i3 = (base + 48) ^ swn;
      float v0 = fmaxf(a0[j] + bpv[0], 0.f) + bf2f(zbuf[i0]);
      float v1 = fmaxf(a1[j] + bpv[1], 0.f) + bf2f(zbuf[i1]);
      float v2 = fmaxf(a2[j] + bpv[2], 0.f) + bf2f(zbuf[i2]);
      float v3 = fmaxf(a3[j] + bpv[3], 0.f) + bf2f(zbuf[i3]);
      zbuf[i0] = f2bf(v0);
      zbuf[i1] = f2bf(v1);
      zbuf[i2] = f2bf(v2);
      zbuf[i3] = f2bf(v3);
    }
    __syncthreads();
  }

  // ---- logits GEMM from zbuf: this WG covers cols [half*1024, +1024) ----
#pragma unroll 1
  for (int nc = 0; nc < 4; ++nc) {
    int colbase = half * 1024 + wv * 256 + nc * 64;
    float bcv[4];
#pragma unroll
    for (int nt = 0; nt < 4; ++nt) bcv[nt] = bc[colbase + nt * 16 + c];
    f32x4 acc[4][4] = {};
#pragma unroll
    for (int kt = 0; kt < 8; ++kt) {
      bf16x8 a[4], bfr[4];
#pragma unroll
      for (int mt = 0; mt < 4; ++mt) {
        int r = mt * 16 + c;
        a[mt] = *(const bf16x8*)&zbuf[r * H_ + ((kt * 32 + g * 8) ^ ((r & 7) << 3))];
      }
#pragma unroll
      for (int nt = 0; nt < 4; ++nt) {
        int col16 = (colbase >> 4) + nt;
        bfr[nt] = *(const bf16x8*)&WcB[(size_t)(col16 * 8 + kt) * 512 + l * 8];
      }
#pragma unroll
      for (int nt = 0; nt < 4; ++nt)
#pragma unroll
        for (int mt = 0; mt < 4; ++mt)
          acc[mt][nt] = __builtin_amdgcn_mfma_f32_16x16x32_bf16(
              a[mt], bfr[nt], acc[mt][nt], 0, 0, 0);
    }
#pragma unroll
    for (int mt = 0; mt < 4; ++mt)
#pragma unroll
      for (int nt = 0; nt < 4; ++nt) {
        int col = colbase + nt * 16 + c;
#pragma unroll
        for (int j = 0; j < 4; ++j) {
          int rt = mt * 16 + g * 4 + j;  // C: row=(l>>4)*4+reg, col=l&15
          out[(size_t)(b * 64 + rt) * OUT_ + col] = acc[mt][nt][j] + bcv[nt];
        }
      }
  }
}

extern "C" void kernel_launch(void* const* d_in, const int* in_sizes, int n_in,
                              void* d_out, int out_size, void* d_ws, size_t ws_size,
                              hipStream_t stream) {
  const float* mol = (const float*)d_in[0];
  const int* pidx = (const int*)d_in[1];
  const float* Wp = (const float*)d_in[2];
  const float* bp = (const float*)d_in[3];
  const float* Wc = (const float*)d_in[4];
  const float* bc = (const float*)d_in[5];
  float* out = (float*)d_out;

  unsigned short* WcB = (unsigned short*)d_ws;                  // 1 MB
  unsigned short* WpB = WcB + (size_t)128 * 8 * 512;            // 128 KB

  pack_kernel<<<144, 256, 0, stream>>>(Wc, Wp, WcB, WpB);
  fused_kernel<<<2 * B_, 256, 0, stream>>>(mol, pidx, bp, WpB, WcB, bc, out);
}

// Round 18
// 99.064 us; speedup vs baseline: 1.1136x; 1.0575x over previous
//
#include <hip/hip_runtime.h>

#define B_ 512
#define L_ 64
#define H_ 256
#define OUT_ 2048

typedef short bf16x8 __attribute__((ext_vector_type(8)));
typedef float f32x4 __attribute__((ext_vector_type(4)));

static __device__ __forceinline__ unsigned short f2bf(float f) {
  union { float f; unsigned int u; } v; v.f = f;
  unsigned int r = (v.u + 0x7FFFu + ((v.u >> 16) & 1u)) >> 16;
  return (unsigned short)r;
}
static __device__ __forceinline__ float bf2f(unsigned short s) {
  union { unsigned int u; float f; } v; v.u = ((unsigned int)s) << 16;
  return v.f;
}

// ---------------------------------------------------------------------------
// Pack Wc (256x2048 f32) and Wp (256x256 f32) into MFMA-fragment-major bf16:
// frag (col16, kt): 64 lanes x 16B; lane l holds
//   B[k = kt*32 + (l>>4)*8 + i][n = col16*16 + (l&15)], i = 0..7.
// ---------------------------------------------------------------------------
__global__ __launch_bounds__(256) void pack_kernel(
    const float* __restrict__ Wc, const float* __restrict__ Wp,
    unsigned short* __restrict__ WcB, unsigned short* __restrict__ WpB) {
  int bid = blockIdx.x;
  const float* W;
  unsigned short* dst;
  int ncols, col16;
  if (bid < 128) { W = Wc; dst = WcB; ncols = OUT_; col16 = bid; }
  else           { W = Wp; dst = WpB; ncols = H_;   col16 = bid - 128; }
  int tid = threadIdx.x, l = tid & 63, q = tid >> 6;
  int n = col16 * 16 + (l & 15), g = l >> 4;
#pragma unroll
  for (int kk = 0; kk < 2; ++kk) {
    int kt = q + kk * 4;
    bf16x8 v;
#pragma unroll
    for (int i = 0; i < 8; ++i)
      v[i] = (short)f2bf(W[(size_t)(kt * 32 + g * 8 + i) * ncols + n]);
    *(bf16x8*)&dst[(size_t)(col16 * 8 + kt) * 512 + l * 8] = v;
  }
}

// ---------------------------------------------------------------------------
// Fused kernel (R10 structure), grid = 2*B_ (WG = (batch, col-half)), 256 thr,
// 4 WG/CU, single round. ONLY change vs R10: the GEMM phase holds all 32
// A-fragments in registers (loaded once after rec, reusing wfr's dead regs)
// and runs 8 nc chunks of 128 cols (32 cols/wave, acc[4][2]) to stay under
// 128 VGPR. Chunk decode: colbase = half*1024 + nc*128 + wv*32 (disjoint).
// zbuf swizzle: ushort index ^= (row&7)<<3.
// ---------------------------------------------------------------------------
__global__ __launch_bounds__(256, 2) void fused_kernel(
    const float* __restrict__ mol, const int* __restrict__ pidx_g,
    const float* __restrict__ bp, const unsigned short* __restrict__ WpB,
    const unsigned short* __restrict__ WcB, const float* __restrict__ bc,
    float* __restrict__ out) {
  __shared__ unsigned short zbuf[65 * H_];  // 33280 B (row 64 = dummy slot)
  __shared__ int pidx[L_];
  __shared__ int cnt_i[64];
  __shared__ unsigned short scale_s[64];
  __shared__ int lvlcnt[64];
  __shared__ int lvlbase[64];
  __shared__ int chkbase[64];
  __shared__ int order_s[64];
  __shared__ int cstart_s[64];
  __shared__ int ccnt_s[64];
  __shared__ int nchunks_s;

  int bid = blockIdx.x;
  int b = bid >> 1, half = bid & 1;
  int tid = threadIdx.x;
  int wv = tid >> 6, l = tid & 63, g = l >> 4, c = l & 15;

  if (tid < 64) pidx[tid] = pidx_g[b * L_ + tid];

  // ---- stage mol -> zbuf (bf16, swizzled 16B chunks) ----
  const float* molb = mol + (size_t)b * L_ * H_;
#pragma unroll
  for (int i = 0; i < 8; ++i) {
    int idx = tid + i * 256;            // 16B chunk id, 0..2047
    int t = idx >> 5, h0 = (idx & 31) * 8;
    f32x4 lo = *(const f32x4*)&molb[t * H_ + h0];
    f32x4 hi = *(const f32x4*)&molb[t * H_ + h0 + 4];
    bf16x8 v;
#pragma unroll
    for (int q = 0; q < 4; ++q) { v[q] = (short)f2bf(lo[q]); v[q + 4] = (short)f2bf(hi[q]); }
    *(bf16x8*)&zbuf[(t * H_ + h0) ^ ((t & 7) << 3)] = v;
  }

  // ---- wave 0: counts, scales, level schedule (LDS-atomic ranks) ----
  if (tid < 64) {
    int t = tid;
    cnt_i[t] = 0;
    lvlcnt[t] = 0;
    int pp = pidx[t];
    if (t >= 1) atomicAdd(&cnt_i[pp], 1);
    int lev = (t == 0) ? 0 : 1;
#pragma unroll
    for (int it = 0; it < 6; ++it) {
      int dp = __shfl(lev, pp);
      int pp2 = __shfl(pp, pp);
      lev += dp;
      pp = pp2;
    }
    int cc = (t >= 1) ? (cnt_i[pidx[t]] - 1) : 0;
    scale_s[t] = (t >= 1 && cc > 0) ? f2bf(1.f / (float)cc) : 0;
    int rank = 0;
    if (t >= 1) rank = atomicAdd(&lvlcnt[lev], 1);
    int lc = lvlcnt[t];
    int nchk = (lc + 15) >> 4;
    int offx = lc, chkx = nchk;
#pragma unroll
    for (int d = 1; d < 64; d <<= 1) {
      int u = __shfl_up(offx, d);
      int v2 = __shfl_up(chkx, d);
      if (t >= d) { offx += u; chkx += v2; }
    }
    lvlbase[t] = offx - lc;
    chkbase[t] = chkx - nchk;
    if (t == 63) nchunks_s = chkx;
    if (t >= 1) {
      int pos = lvlbase[lev] + rank;
      order_s[pos] = t;
      if ((rank & 15) == 0) {
        int cid = chkbase[lev] + (rank >> 4);
        cstart_s[cid] = pos;
        ccnt_s[cid] = min(16, lvlcnt[lev] - rank);
      }
    }
  }
  __syncthreads();

  // ---- sibling means via MFMA: sib^T = mol^T @ G^T ----
  {
    int pv[2][8];
#pragma unroll
    for (int kt = 0; kt < 2; ++kt)
#pragma unroll
      for (int i = 0; i < 8; ++i) pv[kt][i] = pidx[kt * 32 + g * 8 + i];
    bf16x8 bfr[4][2];
#pragma unroll
    for (int nt = 0; nt < 4; ++nt) {
      int tn = nt * 16 + c;
      int pt = pidx[tn];
      unsigned short scl = scale_s[tn];
#pragma unroll
      for (int kt = 0; kt < 2; ++kt) {
        bf16x8 bv;
#pragma unroll
        for (int i = 0; i < 8; ++i) {
          int tp = kt * 32 + g * 8 + i;
          bv[i] = (tp >= 1 && tp != tn && pv[kt][i] == pt) ? (short)scl : (short)0;
        }
        bfr[nt][kt] = bv;
      }
    }
#pragma unroll
    for (int mtl = 0; mtl < 4; ++mtl) {
      int mtg = wv * 4 + mtl;        // global h-tile 0..15
      int colh = mtg * 16 + c;
      bf16x8 afr[2];
#pragma unroll
      for (int kt = 0; kt < 2; ++kt) {
        bf16x8 av;
#pragma unroll
        for (int i = 0; i < 8; ++i) {
          int tp = kt * 32 + g * 8 + i;
          av[i] = (short)zbuf[(tp * H_ + colh) ^ ((tp & 7) << 3)];
        }
        afr[kt] = av;
      }
      f32x4 acc4[4] = {};
#pragma unroll
      for (int nt = 0; nt < 4; ++nt)
#pragma unroll
        for (int kt = 0; kt < 2; ++kt)
          acc4[nt] = __builtin_amdgcn_mfma_f32_16x16x32_bf16(afr[kt], bfr[nt][kt], acc4[nt], 0, 0, 0);
      // scatter: C row=(l>>4)*4+j -> h, col=c -> t (scalar, bank-clean)
#pragma unroll
      for (int nt = 0; nt < 4; ++nt) {
        int ts = nt * 16 + c;
        int swn = (ts & 7) << 3;
#pragma unroll
        for (int j = 0; j < 4; ++j) {
          int h = mtg * 16 + g * 4 + j;
          zbuf[(ts * H_ + h) ^ swn] = f2bf(acc4[nt][j]);
        }
      }
    }
  }

  // ---- Wp B-fragments (per-wave 64-col slice), step-invariant registers ----
  bf16x8 wfr[4][8];
#pragma unroll
  for (int nt = 0; nt < 4; ++nt)
#pragma unroll
    for (int kt = 0; kt < 8; ++kt)
      wfr[nt][kt] = *(const bf16x8*)&WpB[(size_t)((wv * 4 + nt) * 8 + kt) * 512 + l * 8];
  float bpv[4];
#pragma unroll
  for (int nt = 0; nt < 4; ++nt) bpv[nt] = bp[wv * 64 + nt * 16 + c];
  __syncthreads();

  // ---- level-parallel recurrence: one M=16 MFMA round per chunk ----
  int nch = nchunks_s;
  for (int ch = 0; ch < nch; ++ch) {
    int cs = cstart_s[ch], cc = ccnt_s[ch];
    int node = (c < cc) ? order_s[cs + c] : 64;  // A row m = c
    int par = (node < 64) ? pidx[node] : 0;
    int sp = (par & 7) << 3;
    f32x4 a0 = {0.f, 0.f, 0.f, 0.f};
    f32x4 a1 = {0.f, 0.f, 0.f, 0.f};
    f32x4 a2 = {0.f, 0.f, 0.f, 0.f};
    f32x4 a3 = {0.f, 0.f, 0.f, 0.f};
#pragma unroll
    for (int kt = 0; kt < 8; ++kt) {
      bf16x8 av = *(const bf16x8*)&zbuf[par * H_ + ((kt * 32 + g * 8) ^ sp)];
      a0 = __builtin_amdgcn_mfma_f32_16x16x32_bf16(av, wfr[0][kt], a0, 0, 0, 0);
      a1 = __builtin_amdgcn_mfma_f32_16x16x32_bf16(av, wfr[1][kt], a1, 0, 0, 0);
      a2 = __builtin_amdgcn_mfma_f32_16x16x32_bf16(av, wfr[2][kt], a2, 0, 0, 0);
      a3 = __builtin_amdgcn_mfma_f32_16x16x32_bf16(av, wfr[3][kt], a3, 0, 0, 0);
    }
    // epilogue: C row m=(l>>4)*4+j -> node slot m, col=c (scalar, bank-clean)
#pragma unroll
    for (int j = 0; j < 4; ++j) {
      int m = g * 4 + j;
      int nd = (m < cc) ? order_s[cs + m] : 64;
      int swn = (nd & 7) << 3;
      int base = nd * H_ + wv * 64 + c;
      int i0 = (base + 0) ^ swn, i1 = (base + 16) ^ swn;
      int i2 = (base + 32) ^ swn, i3 = (base + 48) ^ swn;
      float v0 = fmaxf(a0[j] + bpv[0], 0.f) + bf2f(zbuf[i0]);
      float v1 = fmaxf(a1[j] + bpv[1], 0.f) + bf2f(zbuf[i1]);
      float v2 = fmaxf(a2[j] + bpv[2], 0.f) + bf2f(zbuf[i2]);
      float v3 = fmaxf(a3[j] + bpv[3], 0.f) + bf2f(zbuf[i3]);
      zbuf[i0] = f2bf(v0);
      zbuf[i1] = f2bf(v1);
      zbuf[i2] = f2bf(v2);
      zbuf[i3] = f2bf(v3);
    }
    __syncthreads();
  }

  // ---- logits GEMM: A-fragments hoisted to registers (reuses dead wfr),
  //      8 nc chunks of 128 cols (32/wave), acc[4][2] ----
  bf16x8 areg[4][8];
#pragma unroll
  for (int mt = 0; mt < 4; ++mt) {
    int r = mt * 16 + c;
#pragma unroll
    for (int kt = 0; kt < 8; ++kt)
      areg[mt][kt] = *(const bf16x8*)&zbuf[r * H_ + ((kt * 32 + g * 8) ^ ((r & 7) << 3))];
  }
#pragma unroll 1
  for (int nc = 0; nc < 8; ++nc) {
    int colbase = half * 1024 + nc * 128 + wv * 32;  // disjoint coverage
    float bcv[2];
#pragma unroll
    for (int nt = 0; nt < 2; ++nt) bcv[nt] = bc[colbase + nt * 16 + c];
    f32x4 acc[4][2] = {};
#pragma unroll
    for (int kt = 0; kt < 8; ++kt) {
      bf16x8 bfr[2];
#pragma unroll
      for (int nt = 0; nt < 2; ++nt) {
        int col16 = ((colbase + nt * 16) >> 4);
        bfr[nt] = *(const bf16x8*)&WcB[(size_t)(col16 * 8 + kt) * 512 + l * 8];
      }
#pragma unroll
      for (int nt = 0; nt < 2; ++nt)
#pragma unroll
        for (int mt = 0; mt < 4; ++mt)
          acc[mt][nt] = __builtin_amdgcn_mfma_f32_16x16x32_bf16(
              areg[mt][kt], bfr[nt], acc[mt][nt], 0, 0, 0);
    }
#pragma unroll
    for (int mt = 0; mt < 4; ++mt)
#pragma unroll
      for (int nt = 0; nt < 2; ++nt) {
        int col = colbase + nt * 16 + c;
#pragma unroll
        for (int j = 0; j < 4; ++j) {
          int rt = mt * 16 + g * 4 + j;  // C: row=(l>>4)*4+reg, col=l&15
          out[(size_t)(b * 64 + rt) * OUT_ + col] = acc[mt][nt][j] + bcv[nt];
        }
      }
  }
}

extern "C" void kernel_launch(void* const* d_in, const int* in_sizes, int n_in,
                              void* d_out, int out_size, void* d_ws, size_t ws_size,
                              hipStream_t stream) {
  const float* mol = (const float*)d_in[0];
  const int* pidx = (const int*)d_in[1];
  const float* Wp = (const float*)d_in[2];
  const float* bp = (const float*)d_in[3];
  const float* Wc = (const float*)d_in[4];
  const float* bc = (const float*)d_in[5];
  float* out = (float*)d_out;

  unsigned short* WcB = (unsigned short*)d_ws;                  // 1 MB
  unsigned short* WpB = WcB + (size_t)128 * 8 * 512;            // 128 KB

  pack_kernel<<<144, 256, 0, stream>>>(Wc, Wp, WcB, WpB);
  fused_kernel<<<2 * B_, 256, 0, stream>>>(mol, pidx, bp, WpB, WcB, bc, out);
}